// Round 7
// baseline (602.247 us; speedup 1.0000x reference)
//
#include <hip/hip_runtime.h>
#include <cstdint>
#include <cstddef>

#define DECAYF 0.99f
#define OMDF   0.01f
#define EPSF   1e-5f
#define MARGIN 0.02f  // hi/lo-split score error ~3e-4; 0.02 = huge headroom, flags ~0.2%

constexpr int N_ROWS = 64 * 2048;   // 131072
constexpr int D      = 128;
constexpr int K      = 1024;
constexpr int SLICES = 4;

typedef __attribute__((ext_vector_type(8))) short bf16x8;   // 8 bf16 = 4 VGPRs
typedef __attribute__((ext_vector_type(4))) float f32x4;

__device__ __forceinline__ unsigned short f2bf(float f) {
    unsigned u = __float_as_uint(f);
    u += 0x7FFFu + ((u >> 16) & 1u);   // RNE
    return (unsigned short)(u >> 16);
}
__device__ __forceinline__ float bf2f(unsigned short h) {
    return __uint_as_float((unsigned)h << 16);
}

// ---------------------------------------------------------------------------
// Convert fp32 -> (hi, lo) bf16 pair.  lo = bf16(v - f32(hi)).
// ---------------------------------------------------------------------------
__global__ __launch_bounds__(256) void convert_x_hl(const float* __restrict__ x,
                                                    unsigned short* __restrict__ xh,
                                                    unsigned short* __restrict__ xl) {
    int i = blockIdx.x * 256 + threadIdx.x;          // N*D/4 threads
    float4 a = ((const float4*)x)[i];
    unsigned short h0 = f2bf(a.x), h1 = f2bf(a.y), h2 = f2bf(a.z), h3 = f2bf(a.w);
    unsigned short l0 = f2bf(a.x - bf2f(h0)), l1 = f2bf(a.y - bf2f(h1));
    unsigned short l2 = f2bf(a.z - bf2f(h2)), l3 = f2bf(a.w - bf2f(h3));
    uint2 ph, pl;
    ph.x = (unsigned)h0 | ((unsigned)h1 << 16); ph.y = (unsigned)h2 | ((unsigned)h3 << 16);
    pl.x = (unsigned)l0 | ((unsigned)l1 << 16); pl.y = (unsigned)l2 | ((unsigned)l3 << 16);
    ((uint2*)xh)[i] = ph;
    ((uint2*)xl)[i] = pl;
}

// ---------------------------------------------------------------------------
// embed -> (eh, el) bf16 pair + eT (fp32 transpose, [D][K]) + cnorm
// ---------------------------------------------------------------------------
__global__ __launch_bounds__(256) void convert_e_hl(const float* __restrict__ e,
                                                    unsigned short* __restrict__ eh,
                                                    unsigned short* __restrict__ el,
                                                    float* __restrict__ eT) {
    int i = blockIdx.x * 256 + threadIdx.x;          // K*D/4 threads
    float4 a = ((const float4*)e)[i];
    unsigned short h0 = f2bf(a.x), h1 = f2bf(a.y), h2 = f2bf(a.z), h3 = f2bf(a.w);
    unsigned short l0 = f2bf(a.x - bf2f(h0)), l1 = f2bf(a.y - bf2f(h1));
    unsigned short l2 = f2bf(a.z - bf2f(h2)), l3 = f2bf(a.w - bf2f(h3));
    uint2 ph, pl;
    ph.x = (unsigned)h0 | ((unsigned)h1 << 16); ph.y = (unsigned)h2 | ((unsigned)h3 << 16);
    pl.x = (unsigned)l0 | ((unsigned)l1 << 16); pl.y = (unsigned)l2 | ((unsigned)l3 << 16);
    ((uint2*)eh)[i] = ph;
    ((uint2*)el)[i] = pl;
    // transpose: element (k, d) -> eT[d][k]
    int base = i * 4;
    int k = base >> 7;
    int d = base & 127;
    eT[(size_t)(d + 0) * K + k] = a.x;
    eT[(size_t)(d + 1) * K + k] = a.y;
    eT[(size_t)(d + 2) * K + k] = a.z;
    eT[(size_t)(d + 3) * K + k] = a.w;
}

__global__ __launch_bounds__(256) void cnorm_kernel(const float* __restrict__ embed,
                                                    float* __restrict__ cnorm) {
    int k = blockIdx.x * 256 + threadIdx.x;
    if (k >= K) return;
    const float4* e4 = (const float4*)(embed + (size_t)k * D);
    float a0 = 0.f, a1 = 0.f, a2 = 0.f, a3 = 0.f;
#pragma unroll
    for (int i = 0; i < D / 4; ++i) {
        float4 v = e4[i];
        a0 += v.x * v.x; a1 += v.y * v.y; a2 += v.z * v.z; a3 += v.w * v.w;
    }
    cnorm[k] = (a0 + a1) + (a2 + a3);
}

// ---------------------------------------------------------------------------
// Split-precision MFMA distance + argmax with margin flagging.
// acc = xh*eh + xl*eh + xh*el (fp32 accum); error ~3e-4 -> MARGIN 0.02.
// Wave owns 32 rows (2 sets); block = 4 waves = 128 rows; grid 1024.
// ---------------------------------------------------------------------------
__global__ __launch_bounds__(256) void mfma_dist(const unsigned short* __restrict__ xh,
                                                 const unsigned short* __restrict__ xl,
                                                 const unsigned short* __restrict__ eh,
                                                 const unsigned short* __restrict__ el,
                                                 const float* __restrict__ cnorm,
                                                 float* __restrict__ out_idx,
                                                 int* __restrict__ idx_i32,
                                                 int* __restrict__ flag_cnt,
                                                 int* __restrict__ flag_list) {
    __shared__ float sb1[128 * 16];
    __shared__ float sb2[128 * 16];
    __shared__ float sid[128 * 16];

    const int tid = threadIdx.x;
    const int wave = tid >> 6;
    const int lane = tid & 63;
    const int l15 = lane & 15;
    const int quad = lane >> 4;
    const int rowbase = blockIdx.x * 128 + wave * 32;

    // preload A-frags (hi+lo): 2 sets x 4 d-chunks
    bf16x8 ah[2][4], al[2][4];
#pragma unroll
    for (int s = 0; s < 2; ++s) {
        int row = rowbase + s * 16 + l15;
#pragma unroll
        for (int c = 0; c < 4; ++c) {
            ah[s][c] = *(const bf16x8*)(xh + (size_t)row * D + c * 32 + quad * 8);
            al[s][c] = *(const bf16x8*)(xl + (size_t)row * D + c * 32 + quad * 8);
        }
    }

    float b1[2][4], b2[2][4], idf[2][4];
#pragma unroll
    for (int s = 0; s < 2; ++s)
#pragma unroll
        for (int r = 0; r < 4; ++r) { b1[s][r] = -3.4e38f; b2[s][r] = -3.4e38f; idf[s][r] = 0.f; }

    for (int cb = 0; cb < K; cb += 16) {
        const int code = cb + l15;
        bf16x8 bh[4], bl[4];
#pragma unroll
        for (int c = 0; c < 4; ++c) {
            bh[c] = *(const bf16x8*)(eh + (size_t)code * D + c * 32 + quad * 8);
            bl[c] = *(const bf16x8*)(el + (size_t)code * D + c * 32 + quad * 8);
        }
        const float cn = cnorm[code];
        const float colf = (float)code;

#pragma unroll
        for (int s = 0; s < 2; ++s) {
            f32x4 acc = {0.f, 0.f, 0.f, 0.f};
#pragma unroll
            for (int c = 0; c < 4; ++c) {
                acc = __builtin_amdgcn_mfma_f32_16x16x32_bf16(al[s][c], bh[c], acc, 0, 0, 0);
                acc = __builtin_amdgcn_mfma_f32_16x16x32_bf16(ah[s][c], bl[c], acc, 0, 0, 0);
                acc = __builtin_amdgcn_mfma_f32_16x16x32_bf16(ah[s][c], bh[c], acc, 0, 0, 0);
            }
#pragma unroll
            for (int r = 0; r < 4; ++r) {
                float sc = 2.0f * acc[r] - cn;
                float old = b1[s][r];
                b1[s][r] = fmaxf(old, sc);
                b2[s][r] = fmaxf(fminf(sc, old), b2[s][r]);
                idf[s][r] = (sc > old) ? colf : idf[s][r];
            }
        }
    }

    // dump per-lane candidates: row lr has 16 candidates (one per l15)
#pragma unroll
    for (int s = 0; s < 2; ++s)
#pragma unroll
        for (int r = 0; r < 4; ++r) {
            int lr = wave * 32 + s * 16 + quad * 4 + r;
            sb1[lr * 16 + l15] = b1[s][r];
            sb2[lr * 16 + l15] = b2[s][r];
            sid[lr * 16 + l15] = idf[s][r];
        }
    __syncthreads();

    if (tid < 128) {
        float bs = sb1[tid * 16], ss = sb2[tid * 16], bi = sid[tid * 16];
#pragma unroll
        for (int j = 1; j < 16; ++j) {
            float v = sb1[tid * 16 + j];
            float w = sb2[tid * 16 + j];
            float id = sid[tid * 16 + j];
            if (v > bs) { ss = fmaxf(bs, w); bi = id; bs = v; }
            else {
                ss = fmaxf(ss, v);
                if (v == bs && id < bi) bi = id;
            }
        }
        int grow = blockIdx.x * 128 + tid;
        out_idx[grow] = bi;
        idx_i32[grow] = (int)bi;
        if (bs - ss < MARGIN) {
            int p = atomicAdd(flag_cnt, 1);
            flag_list[p] = grow;
        }
    }
}

// ---------------------------------------------------------------------------
// Exact fp32 rescore, one block per flagged row (expected ~hundreds).
// eT layout gives coalesced reads: thread t covers codes 4t..4t+3.
// ---------------------------------------------------------------------------
__global__ __launch_bounds__(256) void rescore_rows(const float* __restrict__ x,
                                                    const float* __restrict__ eT,
                                                    const float* __restrict__ cnorm,
                                                    const int* __restrict__ flag_cnt,
                                                    const int* __restrict__ flag_list,
                                                    float* __restrict__ out_idx,
                                                    int* __restrict__ idx_i32) {
    __shared__ float xs[D];
    __shared__ float rbest[4];
    __shared__ int   ridx[4];
    const int cnt = *flag_cnt;
    const int t = threadIdx.x;

    for (int fi = blockIdx.x; fi < cnt; fi += gridDim.x) {
        int grow = flag_list[fi];
        __syncthreads();   // protect xs across iterations
        if (t < 32) *(float4*)&xs[t * 4] = ((const float4*)(x + (size_t)grow * D))[t];
        __syncthreads();

        float a0 = 0.f, a1 = 0.f, a2 = 0.f, a3 = 0.f;
        for (int d = 0; d < D; ++d) {
            float xd = xs[d];
            float4 e = ((const float4*)(eT + (size_t)d * K))[t];
            a0 = fmaf(xd, e.x, a0);
            a1 = fmaf(xd, e.y, a1);
            a2 = fmaf(xd, e.z, a2);
            a3 = fmaf(xd, e.w, a3);
        }
        float s0 = 2.f * a0 - cnorm[4 * t + 0];
        float s1 = 2.f * a1 - cnorm[4 * t + 1];
        float s2 = 2.f * a2 - cnorm[4 * t + 2];
        float s3 = 2.f * a3 - cnorm[4 * t + 3];
        float bs = s0; int bi = 4 * t;
        if (s1 > bs) { bs = s1; bi = 4 * t + 1; }
        if (s2 > bs) { bs = s2; bi = 4 * t + 2; }
        if (s3 > bs) { bs = s3; bi = 4 * t + 3; }
#pragma unroll
        for (int off = 32; off >= 1; off >>= 1) {
            float os = __shfl_down(bs, off, 64);
            int   oi = __shfl_down(bi, off, 64);
            if (os > bs || (os == bs && oi < bi)) { bs = os; bi = oi; }
        }
        if ((t & 63) == 0) { rbest[t >> 6] = bs; ridx[t >> 6] = bi; }
        __syncthreads();
        if (t == 0) {
#pragma unroll
            for (int w = 1; w < 4; ++w)
                if (rbest[w] > bs || (rbest[w] == bs && ridx[w] < bi)) { bs = rbest[w]; bi = ridx[w]; }
            out_idx[grow] = (float)bi;
            idx_i32[grow] = bi;
        }
    }
}

// ---------------------------------------------------------------------------
// Histogram of final indices (LDS-privatized)
// ---------------------------------------------------------------------------
__global__ __launch_bounds__(256) void hist_kernel(const int* __restrict__ idx_i32,
                                                   int* __restrict__ counts_i) {
    __shared__ int h[K];
    for (int i = threadIdx.x; i < K; i += 256) h[i] = 0;
    __syncthreads();
    for (int row = blockIdx.x * 256 + threadIdx.x; row < N_ROWS; row += gridDim.x * 256)
        atomicAdd(&h[idx_i32[row]], 1);
    __syncthreads();
    for (int i = threadIdx.x; i < K; i += 256)
        if (h[i]) atomicAdd(&counts_i[i], h[i]);
}

// ---------------------------------------------------------------------------
// scan counts -> offsets/cursor; ncs, total, smoothed (1 block, 1024 thr)
// ---------------------------------------------------------------------------
__global__ __launch_bounds__(1024) void scan_cluster_kernel(const int* __restrict__ counts_i,
                                                            const float* __restrict__ cluster_size,
                                                            int* __restrict__ offsets,
                                                            int* __restrict__ cursor,
                                                            float* __restrict__ out_ncs,
                                                            float* __restrict__ smoothed) {
    __shared__ int s[1024];
    __shared__ float red[16];
    __shared__ float total_s;
    int k = threadIdx.x;
    int c = counts_i[k];
    s[k] = c;
    __syncthreads();
    for (int off = 1; off < 1024; off <<= 1) {
        int v = (k >= off) ? s[k - off] : 0;
        __syncthreads();
        s[k] += v;
        __syncthreads();
    }
    int offx = s[k] - c;   // exclusive
    offsets[k] = offx;
    cursor[k] = offx;

    float ncs = cluster_size[k] * DECAYF + OMDF * (float)c;
    out_ncs[k] = ncs;

    float v = ncs;
#pragma unroll
    for (int off = 32; off >= 1; off >>= 1) v += __shfl_down(v, off, 64);
    if ((k & 63) == 0) red[k >> 6] = v;
    __syncthreads();
    if (k < 16) {
        float t = red[k];
#pragma unroll
        for (int off = 8; off >= 1; off >>= 1) t += __shfl_down(t, off, 16);
        if (k == 0) total_s = t;
    }
    __syncthreads();
    float total = total_s;
    smoothed[k] = (ncs + EPSF) / (total + (float)K * EPSF) * total;
}

// ---------------------------------------------------------------------------
// scatter row ids into per-code segments
// ---------------------------------------------------------------------------
__global__ __launch_bounds__(256) void scatter_kernel(const int* __restrict__ idx_i32,
                                                      int* __restrict__ cursor,
                                                      int* __restrict__ rowlist) {
    int row = blockIdx.x * 256 + threadIdx.x;
    int code = idx_i32[row];
    int pos = atomicAdd(&cursor[code], 1);
    rowlist[pos] = row;
}

// ---------------------------------------------------------------------------
// Segmented gather-sum: block (k, slice); no LDS -> high occupancy.
// ---------------------------------------------------------------------------
__global__ __launch_bounds__(128) void segsum_gather(const float* __restrict__ x,
                                                     const int* __restrict__ offsets,
                                                     const int* __restrict__ counts_i,
                                                     const int* __restrict__ rowlist,
                                                     float* __restrict__ embed_sum) {
    const int k = blockIdx.x;
    const int sl = blockIdx.y;
    const int d = threadIdx.x;
    const int start = offsets[k];
    const int cnt = counts_i[k];
    const int len = (cnt + SLICES - 1) / SLICES;
    const int lo = sl * len;
    const int hi = min(lo + len, cnt);

    float a0 = 0.f, a1 = 0.f, a2 = 0.f, a3 = 0.f;
    int i = lo;
    for (; i + 4 <= hi; i += 4) {
        int r0 = rowlist[start + i + 0];
        int r1 = rowlist[start + i + 1];
        int r2 = rowlist[start + i + 2];
        int r3 = rowlist[start + i + 3];
        a0 += x[(size_t)r0 * D + d];
        a1 += x[(size_t)r1 * D + d];
        a2 += x[(size_t)r2 * D + d];
        a3 += x[(size_t)r3 * D + d];
    }
    for (; i < hi; ++i) a0 += x[(size_t)rowlist[start + i] * D + d];
    float part = (a0 + a1) + (a2 + a3);
    if (part != 0.f) atomicAdd(&embed_sum[(size_t)k * D + d], part);
}

// ---------------------------------------------------------------------------
// new_embed_avg / new_embed
// ---------------------------------------------------------------------------
__global__ __launch_bounds__(256) void embed_update_kernel(const float* __restrict__ embed_avg,
                                                           const float* __restrict__ embed_sum,
                                                           const float* __restrict__ smoothed,
                                                           float* __restrict__ out_nea,
                                                           float* __restrict__ out_ne) {
    int t = blockIdx.x * 256 + threadIdx.x;
    float4 ea = ((const float4*)embed_avg)[t];
    float4 es = ((const float4*)embed_sum)[t];
    float sm = smoothed[t >> 5];
    float4 nea;
    nea.x = ea.x * DECAYF + OMDF * es.x;
    nea.y = ea.y * DECAYF + OMDF * es.y;
    nea.z = ea.z * DECAYF + OMDF * es.z;
    nea.w = ea.w * DECAYF + OMDF * es.w;
    ((float4*)out_nea)[t] = nea;
    float4 ne;
    ne.x = nea.x / sm; ne.y = nea.y / sm; ne.z = nea.z / sm; ne.w = nea.w / sm;
    ((float4*)out_ne)[t] = ne;
}

// ---------------------------------------------------------------------------
// quantized[row] = embed[idx[row]]  (runs last: overwrites xh/xl scratch)
// ---------------------------------------------------------------------------
__global__ __launch_bounds__(256) void gather_kernel(const float* __restrict__ embed,
                                                     const int* __restrict__ idx_i32,
                                                     float* __restrict__ quant) {
    int t = blockIdx.x * 256 + threadIdx.x;
    int row = t >> 5;
    int j = t & 31;
    int k = idx_i32[row];
    ((float4*)quant)[(size_t)row * 32 + j] = ((const float4*)embed)[(size_t)k * 32 + j];
}

// ---------------------------------------------------------------------------
extern "C" void kernel_launch(void* const* d_in, const int* in_sizes, int n_in,
                              void* d_out, int out_size, void* d_ws, size_t ws_size,
                              hipStream_t stream) {
    const float* x            = (const float*)d_in[0];
    const float* embed        = (const float*)d_in[1];
    const float* embed_avg    = (const float*)d_in[2];
    const float* cluster_size = (const float*)d_in[3];

    float* out       = (float*)d_out;
    float* out_quant = out;
    float* out_idx   = out_quant + (size_t)N_ROWS * D;
    float* out_ne    = out_idx + N_ROWS;
    float* out_ncs   = out_ne + (size_t)K * D;
    float* out_nea   = out_ncs + K;

    // xh/xl scratch in the quantized output region (2 x 32 MB, overwritten last)
    unsigned short* xh = (unsigned short*)out_quant;
    unsigned short* xl = xh + (size_t)N_ROWS * D;

    // workspace (~3.2 MB)
    int*   counts_i  = (int*)d_ws;                        // K
    int*   flag_cnt  = counts_i + K;                      // 1 (+3 pad)
    int*   idx_i32   = counts_i + K + 4;                  // N
    int*   flag_list = idx_i32 + N_ROWS;                  // N
    int*   offsets   = flag_list + N_ROWS;                // K
    int*   cursor    = offsets + K;                       // K
    int*   rowlist   = cursor + K;                        // N
    float* cnorm     = (float*)(rowlist + N_ROWS);        // K
    float* smoothed  = cnorm + K;                         // K
    float* embed_sum = smoothed + K;                      // K*D
    float* eT        = embed_sum + (size_t)K * D;         // K*D (transposed, fp32)
    unsigned short* eh = (unsigned short*)(eT + (size_t)K * D);  // K*D bf16
    unsigned short* el = eh + (size_t)K * D;                     // K*D bf16

    hipMemsetAsync(counts_i, 0, (K + 4) * sizeof(int), stream);
    hipMemsetAsync(embed_sum, 0, (size_t)K * D * sizeof(float), stream);

    convert_x_hl<<<(N_ROWS * D / 4) / 256, 256, 0, stream>>>(x, xh, xl);
    convert_e_hl<<<(K * D / 4) / 256, 256, 0, stream>>>(embed, eh, el, eT);
    cnorm_kernel<<<(K + 255) / 256, 256, 0, stream>>>(embed, cnorm);
    mfma_dist<<<N_ROWS / 128, 256, 0, stream>>>(xh, xl, eh, el, cnorm, out_idx, idx_i32,
                                                flag_cnt, flag_list);
    rescore_rows<<<1024, 256, 0, stream>>>(x, eT, cnorm, flag_cnt, flag_list, out_idx, idx_i32);
    hist_kernel<<<64, 256, 0, stream>>>(idx_i32, counts_i);
    scan_cluster_kernel<<<1, 1024, 0, stream>>>(counts_i, cluster_size, offsets, cursor,
                                                out_ncs, smoothed);
    scatter_kernel<<<N_ROWS / 256, 256, 0, stream>>>(idx_i32, cursor, rowlist);
    segsum_gather<<<dim3(K, SLICES), 128, 0, stream>>>(x, offsets, counts_i, rowlist, embed_sum);
    embed_update_kernel<<<(K * D / 4) / 256, 256, 0, stream>>>(embed_avg, embed_sum, smoothed,
                                                               out_nea, out_ne);
    gather_kernel<<<(N_ROWS * 32) / 256, 256, 0, stream>>>(embed, idx_i32, out_quant);
}